// Round 1
// baseline (682.611 us; speedup 1.0000x reference)
//
#include <hip/hip_runtime.h>
#include <math.h>

// ---------------------------------------------------------------------------
// SimpleAttention: out[b,n] = mean_h softmax(q[b,h,n,:]·k[b,h,:,:] * SCALE)[n]
// q,k from qk = x @ W_qk.T + b_qk ; x:[4,2048,768] W:[1536,768] b:[1536]
// B=4 N=2048 H=12 D=64 SCALE=0.125
// ---------------------------------------------------------------------------

#define B_ 4
#define N_ 2048
#define H_ 12
#define D_ 64
#define C_ 768
#define SCALE_ 0.125f
#define TK 32

// ---------------- Kernel A: QK projection GEMM (fp32) ----------------------
// M = B*N = 8192 rows of x ; cols c in [0,1536). Tile 64x64, thread 4x4.
// Output scattered into q[b,h,n,d] / k[b,h,n,d] layout for kernel B.
__global__ __launch_bounds__(256) void proj_kernel(
    const float* __restrict__ x, const float* __restrict__ W,
    const float* __restrict__ bias, float* __restrict__ qws,
    float* __restrict__ kws) {
  __shared__ float Xs[TK][68];  // [k][m], pad 68 keeps float4 alignment
  __shared__ float Ws[TK][68];  // [k][c]
  const int t = threadIdx.x;
  const int bm = blockIdx.y * 64;
  const int bc = blockIdx.x * 64;
  const int tr = t >> 4, tc = t & 15;
  float acc[4][4] = {};
  for (int k0 = 0; k0 < C_; k0 += TK) {
#pragma unroll
    for (int i = 0; i < 2; ++i) {
      int f = t + i * 256;        // 0..511 float4 id
      int r = f >> 3;             // row 0..63
      int kk = (f & 7) << 2;      // 0..28
      float4 vx = *(const float4*)(x + (size_t)(bm + r) * C_ + k0 + kk);
      Xs[kk + 0][r] = vx.x; Xs[kk + 1][r] = vx.y;
      Xs[kk + 2][r] = vx.z; Xs[kk + 3][r] = vx.w;
      float4 vw = *(const float4*)(W + (size_t)(bc + r) * C_ + k0 + kk);
      Ws[kk + 0][r] = vw.x; Ws[kk + 1][r] = vw.y;
      Ws[kk + 2][r] = vw.z; Ws[kk + 3][r] = vw.w;
    }
    __syncthreads();
#pragma unroll
    for (int kk = 0; kk < TK; ++kk) {
      float4 a = *(const float4*)&Xs[kk][tr << 2];
      float4 bv = *(const float4*)&Ws[kk][tc << 2];
      float av[4] = {a.x, a.y, a.z, a.w};
      float bb[4] = {bv.x, bv.y, bv.z, bv.w};
#pragma unroll
      for (int i = 0; i < 4; ++i)
#pragma unroll
        for (int j = 0; j < 4; ++j) acc[i][j] += av[i] * bb[j];
    }
    __syncthreads();
  }
  // epilogue: bias + scatter to q/k [b,h,n,d]
#pragma unroll
  for (int i = 0; i < 4; ++i) {
    int m = bm + (tr << 2) + i;
    int b = m >> 11, n = m & (N_ - 1);
#pragma unroll
    for (int j = 0; j < 4; ++j) {
      int c = bc + (tc << 2) + j;
      float v = acc[i][j] + bias[c];
      int cc = (c < C_) ? c : (c - C_);
      int h = cc >> 6, d = cc & 63;
      float* dst = (c < C_) ? qws : kws;
      dst[(((size_t)(b * H_ + h) * N_ + n) << 6) + d] = v;
    }
  }
}

// ---------------- Kernel B: online-softmax diagonal -------------------------
// Block = (qtile of 64 queries, h, b). q-tile resident in LDS, sweep 32 key
// tiles; 4x4 register-blocked score tile; 4 threads per query row do the
// online max/sum update via shfl; diagonal captured when kt == qt.
__global__ __launch_bounds__(256) void attn_diag_kernel(
    const float* __restrict__ qws, const float* __restrict__ kws,
    float* __restrict__ part) {
  const int qt = blockIdx.x;  // 0..31
  const int h = blockIdx.y;   // 0..11
  const int b = blockIdx.z;   // 0..3
  const float* qb = qws + (((size_t)(b * H_ + h) * N_ + qt * 64) << 6);
  const float* kb = kws + (((size_t)(b * H_ + h) * N_) << 6);
  __shared__ float qs[64][68];  // [d][row]
  __shared__ float ks[64][68];  // [d][col]
  __shared__ float sc[64][68];  // [row][key]
  const int t = threadIdx.x;
  const int tr = t >> 4, tc = t & 15;
  const int r4 = t >> 2, p = t & 3;  // softmax: row r4 owned by 4 threads

  // load q tile: qs[d][r]
#pragma unroll
  for (int i = 0; i < 4; ++i) {
    int f = t + i * 256;      // 0..1023 float4 id
    int r = f >> 4;           // 0..63
    int d0 = (f & 15) << 2;   // 0..60
    float4 v = *(const float4*)(qb + r * 64 + d0);
    qs[d0 + 0][r] = v.x; qs[d0 + 1][r] = v.y;
    qs[d0 + 2][r] = v.z; qs[d0 + 3][r] = v.w;
  }

  float m_run = -3.0e38f, l_run = 0.0f, sdiag = 0.0f;

  for (int kt = 0; kt < N_ / 64; ++kt) {
    __syncthreads();  // previous iter's sc reads done before ks rewrite
#pragma unroll
    for (int i = 0; i < 4; ++i) {
      int f = t + i * 256;
      int r = f >> 4;
      int d0 = (f & 15) << 2;
      float4 v = *(const float4*)(kb + (size_t)(kt * 64 + r) * 64 + d0);
      ks[d0 + 0][r] = v.x; ks[d0 + 1][r] = v.y;
      ks[d0 + 2][r] = v.z; ks[d0 + 3][r] = v.w;
    }
    __syncthreads();

    float acc[4][4] = {};
#pragma unroll
    for (int d = 0; d < 64; ++d) {
      float4 a = *(const float4*)&qs[d][tr << 2];
      float4 bv = *(const float4*)&ks[d][tc << 2];
      float av[4] = {a.x, a.y, a.z, a.w};
      float bb[4] = {bv.x, bv.y, bv.z, bv.w};
#pragma unroll
      for (int i = 0; i < 4; ++i)
#pragma unroll
        for (int j = 0; j < 4; ++j) acc[i][j] += av[i] * bb[j];
    }
#pragma unroll
    for (int i = 0; i < 4; ++i)
#pragma unroll
      for (int j = 0; j < 4; ++j)
        sc[(tr << 2) + i][(tc << 2) + j] = acc[i][j] * SCALE_;
    __syncthreads();

    // online softmax update: 4 threads per row, 16 keys each
    float tmax = -3.0e38f;
#pragma unroll
    for (int u = 0; u < 16; ++u) tmax = fmaxf(tmax, sc[r4][(p << 4) + u]);
    tmax = fmaxf(tmax, __shfl_xor(tmax, 1, 4));
    tmax = fmaxf(tmax, __shfl_xor(tmax, 2, 4));
    float mnew = fmaxf(m_run, tmax);
    float s = 0.0f;
#pragma unroll
    for (int u = 0; u < 16; ++u) s += __expf(sc[r4][(p << 4) + u] - mnew);
    s += __shfl_xor(s, 1, 4);
    s += __shfl_xor(s, 2, 4);
    l_run = l_run * __expf(m_run - mnew) + s;
    m_run = mnew;
    if (kt == qt) sdiag = sc[r4][r4];  // broadcast read, all 4 threads
  }

  if (p == 0) {
    float w = __expf(sdiag - m_run) / l_run;
    part[(size_t)(b * H_ + h) * N_ + qt * 64 + r4] = w;
  }
}

// ---------------- Kernel C: mean over heads ---------------------------------
__global__ __launch_bounds__(256) void reduce_kernel(
    const float* __restrict__ part, float* __restrict__ out) {
  int g = blockIdx.x * 256 + threadIdx.x;  // 0..8191
  if (g >= B_ * N_) return;
  int b = g >> 11, n = g & (N_ - 1);
  float s = 0.0f;
#pragma unroll
  for (int h = 0; h < H_; ++h) s += part[(size_t)(b * H_ + h) * N_ + n];
  out[g] = s * (1.0f / (float)H_);
}

// ---------------------------------------------------------------------------
extern "C" void kernel_launch(void* const* d_in, const int* in_sizes, int n_in,
                              void* d_out, int out_size, void* d_ws,
                              size_t ws_size, hipStream_t stream) {
  const float* x = (const float*)d_in[0];
  const float* W = (const float*)d_in[1];
  const float* bias = (const float*)d_in[2];
  float* out = (float*)d_out;

  const size_t qk_elems = (size_t)B_ * H_ * N_ * D_;  // 6,291,456
  float* qws = (float*)d_ws;
  float* kws = qws + qk_elems;
  float* part = kws + qk_elems;

  proj_kernel<<<dim3(2 * C_ / 64, B_ * N_ / 64), 256, 0, stream>>>(x, W, bias,
                                                                   qws, kws);
  attn_diag_kernel<<<dim3(N_ / 64, H_, B_), 256, 0, stream>>>(qws, kws, part);
  reduce_kernel<<<(B_ * N_ + 255) / 256, 256, 0, stream>>>(part, out);
}

// Round 2
// 170.209 us; speedup vs baseline: 4.0104x; 4.0104x over previous
//
#include <hip/hip_runtime.h>
#include <math.h>

// ---------------------------------------------------------------------------
// SimpleAttention via fp16 MFMA:
//   qk = x @ W_qk.T + b  ->  q,k [B,H,N,D] fp16
//   out[b,n] = mean_h softmax(q_bhn . k_bh* * 0.125)[n]
// B=4 N=2048 H=12 D=64 C=768
// ---------------------------------------------------------------------------

#define B_ 4
#define N_ 2048
#define H_ 12
#define D_ 64
#define C_ 768
#define TWO_C 1536
#define SCALE_ 0.125f

typedef _Float16 half8 __attribute__((ext_vector_type(8)));
typedef _Float16 half4 __attribute__((ext_vector_type(4)));
typedef float floatx4 __attribute__((ext_vector_type(4)));

// ---------------- fp32 -> fp16 conversion -----------------------------------
__global__ __launch_bounds__(256) void conv_kernel(const float* __restrict__ in,
                                                   _Float16* __restrict__ out,
                                                   int n4) {
  int i = blockIdx.x * 256 + threadIdx.x;
  if (i >= n4) return;
  float4 v = ((const float4*)in)[i];
  half4 o;
  o[0] = (_Float16)v.x; o[1] = (_Float16)v.y;
  o[2] = (_Float16)v.z; o[3] = (_Float16)v.w;
  ((half4*)out)[i] = o;
}

// ---------------- proj: C = x @ W^T + b, scattered to q/k -------------------
// M=8192, N=1536, K=768. 128x128 tile, 4 waves (2x2), 16x16x32 f16 MFMA.
// LDS tiles [128][32] fp16: 64B row stride spreads b128 frag reads uniformly.
__global__ __launch_bounds__(256) void proj_kernel(
    const _Float16* __restrict__ xh, const _Float16* __restrict__ wh,
    const float* __restrict__ bias, _Float16* __restrict__ qh,
    _Float16* __restrict__ kh) {
  __shared__ _Float16 As[128][32];
  __shared__ _Float16 Bs[128][32];
  const int t = threadIdx.x;
  const int l = t & 63;
  const int w = t >> 6;
  const int wr = w >> 1, wc = w & 1;
  const int bm = blockIdx.y * 128;
  const int bc = blockIdx.x * 128;

  floatx4 acc[4][4] = {};

  for (int k0 = 0; k0 < C_; k0 += 32) {
    __syncthreads();
#pragma unroll
    for (int i = 0; i < 2; ++i) {
      int f = t + i * 256;
      int row = f >> 2;
      int ko = (f & 3) * 8;
      *(half8*)&As[row][ko] =
          *(const half8*)(xh + (size_t)(bm + row) * C_ + k0 + ko);
      *(half8*)&Bs[row][ko] =
          *(const half8*)(wh + (size_t)(bc + row) * C_ + k0 + ko);
    }
    __syncthreads();

    half8 af[4], bf[4];
#pragma unroll
    for (int fr = 0; fr < 4; ++fr)
      af[fr] = *(const half8*)&As[wr * 64 + fr * 16 + (l & 15)][(l >> 4) * 8];
#pragma unroll
    for (int fc = 0; fc < 4; ++fc)
      bf[fc] = *(const half8*)&Bs[wc * 64 + fc * 16 + (l & 15)][(l >> 4) * 8];
#pragma unroll
    for (int fr = 0; fr < 4; ++fr)
#pragma unroll
      for (int fc = 0; fc < 4; ++fc)
        acc[fr][fc] = __builtin_amdgcn_mfma_f32_16x16x32_f16(
            af[fr], bf[fc], acc[fr][fc], 0, 0, 0);
  }

  // epilogue: + bias, scatter into q/k [b,h,n,d] fp16
  // C frag mapping: col = l&15, row = (l>>4)*4 + j
#pragma unroll
  for (int fr = 0; fr < 4; ++fr) {
#pragma unroll
    for (int fc = 0; fc < 4; ++fc) {
#pragma unroll
      for (int j = 0; j < 4; ++j) {
        int m = bm + wr * 64 + fr * 16 + ((l >> 4) << 2) + j;
        int c = bc + wc * 64 + fc * 16 + (l & 15);
        float v = acc[fr][fc][j] + bias[c];
        int b = m >> 11, n = m & (N_ - 1);
        int cc = (c < C_) ? c : c - C_;
        int hh = cc >> 6, d = cc & 63;
        _Float16* dst = (c < C_) ? qh : kh;
        dst[((((size_t)b * H_ + hh) * N_ + n) << 6) + d] = (_Float16)v;
      }
    }
  }
}

// ---------------- attn: online-softmax diagonal via MFMA --------------------
// Block = (qt, h, b), 4 waves. Wave owns 16 query rows (Q frags in regs),
// sweeps 32 key tiles of 64. K staged as two [64][32] LDS chunks (64B stride).
// Softmax entirely in registers on C fragments via width-16 shuffles.
__global__ __launch_bounds__(256) void attn_kernel(
    const _Float16* __restrict__ qh, const _Float16* __restrict__ kh,
    float* __restrict__ part) {
  __shared__ _Float16 ks[2][64][32];
  const int t = threadIdx.x;
  const int l = t & 63;
  const int w = t >> 6;
  const int qt = blockIdx.x;
  const int h = blockIdx.y;
  const int b = blockIdx.z;
  const _Float16* qb = qh + (((size_t)(b * H_ + h) * N_ + qt * 64) << 6);
  const _Float16* kb = kh + (((size_t)(b * H_ + h) * N_) << 6);

  // Q fragments: wave rows w*16 + (l&15), d split in two k-halves
  half8 qf[2];
#pragma unroll
  for (int kd = 0; kd < 2; ++kd)
    qf[kd] = *(const half8*)(qb + (size_t)(w * 16 + (l & 15)) * 64 + kd * 32 +
                             (l >> 4) * 8);

  float m_run[4], l_run[4], sdiag[4];
#pragma unroll
  for (int j = 0; j < 4; ++j) {
    m_run[j] = -1e30f;
    l_run[j] = 0.0f;
    sdiag[j] = 0.0f;
  }

  for (int kt = 0; kt < N_ / 64; ++kt) {
    __syncthreads();  // previous iteration's frag reads done
#pragma unroll
    for (int i = 0; i < 2; ++i) {
      int f = t + i * 256;
      int row = f >> 3;
      int doff = (f & 7) * 8;
      half8 v = *(const half8*)(kb + (size_t)(kt * 64 + row) * 64 + doff);
      *(half8*)&ks[doff >> 5][row][doff & 31] = v;
    }
    __syncthreads();

    floatx4 acc[4] = {};
#pragma unroll
    for (int kd = 0; kd < 2; ++kd) {
#pragma unroll
      for (int fc = 0; fc < 4; ++fc) {
        half8 bf = *(const half8*)&ks[kd][fc * 16 + (l & 15)][(l >> 4) * 8];
        acc[fc] =
            __builtin_amdgcn_mfma_f32_16x16x32_f16(qf[kd], bf, acc[fc], 0, 0, 0);
      }
    }

    // scores: lane holds rows (l>>4)*4+j (wave-local +w*16), cols fc*16+(l&15)
    float s[4][4];
#pragma unroll
    for (int fc = 0; fc < 4; ++fc)
#pragma unroll
      for (int j = 0; j < 4; ++j) s[fc][j] = acc[fc][j] * SCALE_;

#pragma unroll
    for (int j = 0; j < 4; ++j) {
      float mx = fmaxf(fmaxf(s[0][j], s[1][j]), fmaxf(s[2][j], s[3][j]));
#pragma unroll
      for (int m = 1; m < 16; m <<= 1) mx = fmaxf(mx, __shfl_xor(mx, m, 16));
      float mnew = fmaxf(m_run[j], mx);
      float sum = __expf(s[0][j] - mnew) + __expf(s[1][j] - mnew) +
                  __expf(s[2][j] - mnew) + __expf(s[3][j] - mnew);
#pragma unroll
      for (int m = 1; m < 16; m <<= 1) sum += __shfl_xor(sum, m, 16);
      l_run[j] = l_run[j] * __expf(m_run[j] - mnew) + sum;
      m_run[j] = mnew;
    }

    if (kt == qt) {
#pragma unroll
      for (int fc = 0; fc < 4; ++fc)
#pragma unroll
        for (int j = 0; j < 4; ++j) {
          int row = w * 16 + ((l >> 4) << 2) + j;
          int col = fc * 16 + (l & 15);
          if (row == col) sdiag[j] = s[fc][j];
        }
    }
  }

  // gather sdiag to all lanes of each 16-lane row group (one owner nonzero)
#pragma unroll
  for (int j = 0; j < 4; ++j)
#pragma unroll
    for (int m = 1; m < 16; m <<= 1) sdiag[j] += __shfl_xor(sdiag[j], m, 16);

  if ((l & 15) == 0) {
#pragma unroll
    for (int j = 0; j < 4; ++j) {
      int row = qt * 64 + w * 16 + ((l >> 4) << 2) + j;
      float wgt = __expf(sdiag[j] - m_run[j]) / l_run[j];
      part[(size_t)(b * H_ + h) * N_ + row] = wgt;
    }
  }
}

// ---------------- mean over heads -------------------------------------------
__global__ __launch_bounds__(256) void reduce_kernel(
    const float* __restrict__ part, float* __restrict__ out) {
  int g = blockIdx.x * 256 + threadIdx.x;
  if (g >= B_ * N_) return;
  int b = g >> 11, n = g & (N_ - 1);
  float s = 0.0f;
#pragma unroll
  for (int hh = 0; hh < H_; ++hh) s += part[(size_t)(b * H_ + hh) * N_ + n];
  out[g] = s * (1.0f / (float)H_);
}

// ---------------------------------------------------------------------------
extern "C" void kernel_launch(void* const* d_in, const int* in_sizes, int n_in,
                              void* d_out, int out_size, void* d_ws,
                              size_t ws_size, hipStream_t stream) {
  const float* x = (const float*)d_in[0];
  const float* W = (const float*)d_in[1];
  const float* bias = (const float*)d_in[2];
  float* out = (float*)d_out;

  char* ws = (char*)d_ws;
  _Float16* xh = (_Float16*)ws;                       // 8192*768
  _Float16* wh = (_Float16*)(ws + 12582912);          // 1536*768
  _Float16* qh = (_Float16*)(ws + 14942208);          // B*H*N*D
  _Float16* kh = (_Float16*)(ws + 27525120);          // B*H*N*D
  float* part = (float*)(ws + 40108032);              // B*H*N fp32

  conv_kernel<<<(1572864 + 255) / 256, 256, 0, stream>>>(x, xh, 1572864);
  conv_kernel<<<(294912 + 255) / 256, 256, 0, stream>>>(W, wh, 294912);
  proj_kernel<<<dim3(TWO_C / 128, 8192 / 128), 256, 0, stream>>>(xh, wh, bias,
                                                                 qh, kh);
  attn_kernel<<<dim3(N_ / 64, H_, B_), 256, 0, stream>>>(qh, kh, part);
  reduce_kernel<<<(B_ * N_ + 255) / 256, 256, 0, stream>>>(part, out);
}